// Round 2
// baseline (1374.377 us; speedup 1.0000x reference)
//
#include <hip/hip_runtime.h>
#include <hip/hip_bf16.h>

typedef unsigned int uint;
typedef unsigned short ushort;
typedef __attribute__((ext_vector_type(8))) short short8;   // 8 bf16 (4 VGPRs)
typedef __attribute__((ext_vector_type(4))) float f32x4;

#define SCALEF 0.08838834764831845f   // 128^-0.5
#define NBINS 4096
#define CAND_MAX 4096
#define SEL_MAX 1024
#define MARGIN 0.08f      // >= 2x worst-case bf16 score error (~0.01)
#define T_LOOSE 3.3f      // static collect threshold (s64 ~ 3.8 for this data)
#define HIST_MIN 2.5f     // histogram prefilter

static __device__ __forceinline__ ushort f2bf(float f) {
  uint u = __float_as_uint(f);
  uint r = ((u >> 16) & 1u) + 0x7fffu;   // RNE
  return (ushort)((u + r) >> 16);
}

// ---------------- K0: Q/K projection (fp32 -> bf16), 8 rows per block ----
__global__ __launch_bounds__(128) void k_proj(const float* __restrict__ x,
    const float* __restrict__ Wq, const float* __restrict__ bq,
    const float* __restrict__ Wk, const float* __restrict__ bk,
    ushort* __restrict__ Qb, ushort* __restrict__ Kb) {
  int bid = blockIdx.x;             // rows [bid*8, bid*8+8)
  int h = threadIdx.x;              // 0..127
  __shared__ float xs[128];         // 8 rows x 16
  xs[h] = x[(size_t)bid * 128 + h];
  float wq[16], wk[16];
#pragma unroll
  for (int d = 0; d < 16; d++) { wq[d] = Wq[d * 128 + h]; wk[d] = Wk[d * 128 + h]; }
  float q0 = bq[h], k0 = bk[h];
  __syncthreads();
#pragma unroll
  for (int r = 0; r < 8; r++) {
    float q = q0, k = k0;
#pragma unroll
    for (int d = 0; d < 16; d++) { float xv = xs[r * 16 + d]; q += xv * wq[d]; k += xv * wk[d]; }
    size_t o = (size_t)(bid * 8 + r) * 128 + h;
    Qb[o] = f2bf(q); Kb[o] = f2bf(k);
  }
}

// ---------------- shared tile compute: 128x128 bf16 MFMA, K=128 ----
static __device__ __forceinline__ void tile_mfma(const ushort* __restrict__ Qb,
    const ushort* __restrict__ Kb, int b, int tm, int tn, int tid,
    char* lds, f32x4 acc[4][4]) {
  const char* Aq = (const char*)(Qb + (size_t)b * 131072) + (size_t)tm * 32768;
  const char* Bk = (const char*)(Kb + (size_t)b * 131072) + (size_t)tn * 32768;
#pragma unroll
  for (int i = 0; i < 8; i++) {
    int slot = tid + 256 * i;       // 0..2047 = 128 rows x 16 chunks
    int row = slot >> 4;
    int c = slot & 15;
    int gc = c ^ (row & 7);         // swizzled source chunk (pre-swizzled global read)
    *(uint4*)(lds + row * 256 + c * 16) = *(const uint4*)(Aq + row * 256 + gc * 16);
    *(uint4*)(lds + 32768 + row * 256 + c * 16) = *(const uint4*)(Bk + row * 256 + gc * 16);
  }
  __syncthreads();
  int w = tid >> 6, lane = tid & 63;
  int wm = (w >> 1) * 64, wn = (w & 1) * 64;   // 2x2 wave grid, 64x64 each
  int lr = lane & 15, lk = lane >> 4;
#pragma unroll
  for (int i = 0; i < 4; i++)
#pragma unroll
    for (int j = 0; j < 4; j++) acc[i][j] = (f32x4){0.f, 0.f, 0.f, 0.f};
#pragma unroll
  for (int ks = 0; ks < 4; ks++) {
    short8 af[4], bf2[4];
#pragma unroll
    for (int f = 0; f < 4; f++) {
      int ra = wm + f * 16 + lr;
      int ca = (ks * 4 + lk) ^ (ra & 7);
      af[f] = *(const short8*)(lds + ra * 256 + ca * 16);
      int rb = wn + f * 16 + lr;
      int cb = (ks * 4 + lk) ^ (rb & 7);
      bf2[f] = *(const short8*)(lds + 32768 + rb * 256 + cb * 16);
    }
#pragma unroll
    for (int fm = 0; fm < 4; fm++)
#pragma unroll
      for (int fn = 0; fn < 4; fn++)
        acc[fm][fn] = __builtin_amdgcn_mfma_f32_16x16x32_bf16(af[fm], bf2[fn], acc[fm][fn], 0, 0, 0);
  }
}

// ---------------- K1: single MFMA pass: prefiltered histogram + loose collect ----
__global__ __launch_bounds__(256) void k_score_hist(const ushort* __restrict__ Qb,
    const ushort* __restrict__ Kb, uint* __restrict__ ghist,
    uint* __restrict__ ccnt, int* __restrict__ cidx) {
  __shared__ __align__(16) char lds[65536];
  int b = blockIdx.x >> 6;
  int t = blockIdx.x & 63;
  int tm = t >> 3, tn = t & 7;
  int tid = threadIdx.x;
  f32x4 acc[4][4];
  tile_mfma(Qb, Kb, b, tm, tn, tid, lds, acc);
  int w = tid >> 6, lane = tid & 63;
  int wm = (w >> 1) * 64, wn = (w & 1) * 64;
  int lr = lane & 15, lk = lane >> 4;
#pragma unroll
  for (int fm = 0; fm < 4; fm++)
#pragma unroll
    for (int fn = 0; fn < 4; fn++)
#pragma unroll
      for (int r = 0; r < 4; r++) {
        float v = acc[fm][fn][r] * SCALEF;
        if (v >= HIST_MIN) {
          uint u = __float_as_uint(v) | 0x80000000u;    // order-map (v>0 here)
          atomicAdd(&ghist[b * NBINS + (u >> 20)], 1u);
          if (v >= T_LOOSE) {
            int mrow = tm * 128 + wm + fm * 16 + lk * 4 + r;
            int ncol = tn * 128 + wn + fn * 16 + lr;
            uint pos = atomicAdd(&ccnt[b], 1u);
            if (pos < CAND_MAX) cidx[b * CAND_MAX + pos] = mrow * 1024 + ncol;
          }
        }
      }
}

// ---------------- K2: refined threshold + safety verification ----
__global__ __launch_bounds__(256) void k_thresh(const uint* __restrict__ ghist,
    const uint* __restrict__ ccnt, float* __restrict__ tcut, int* __restrict__ flag) {
  int b = blockIdx.x;
  int tid = threadIdx.x;
  __shared__ uint hsh[NBINS];
  __shared__ uint csuf[256];
  __shared__ uint total_sh;
  for (int i = tid; i < NBINS; i += 256) hsh[i] = ghist[b * NBINS + i];
  __syncthreads();
  uint s = 0;
#pragma unroll
  for (int i = 0; i < 16; i++) s += hsh[tid * 16 + i];
  csuf[tid] = s;
  __syncthreads();
  if (tid == 0) {                      // exclusive suffix over 256 chunk sums
    uint run = 0;
    for (int t2 = 255; t2 >= 0; t2--) { uint tmp = csuf[t2]; csuf[t2] = run; run += tmp; }
    total_sh = run;
  }
  __syncthreads();
  if (total_sh < 64) {                 // degenerate: 64th value below HIST_MIN
    if (tid == 0) { tcut[b] = -1e30f; flag[b] = 1; }
    return;
  }
  uint above = csuf[tid];
  if (above < 64) {
    uint run = above;
    for (int i = 15; i >= 0; i--) {
      run += hsh[tid * 16 + i];
      if (run >= 64) {                 // bin containing the 64th-largest approx value
        uint umin = ((uint)(tid * 16 + i)) << 20;
        float lower = (umin & 0x80000000u) ? __uint_as_float(umin ^ 0x80000000u)
                                           : __uint_as_float(~umin);
        tcut[b] = lower - MARGIN;
        // pass-0 candidate set valid iff every true-top-64's approx >= T_LOOSE
        flag[b] = (lower < T_LOOSE + MARGIN) || (ccnt[b] > CAND_MAX) ? 1 : 0;
        break;
      }
    }
  }
}

// ---------------- K3: fallback collect (early-exit unless flagged) ----
__global__ __launch_bounds__(256) void k_fallback(const ushort* __restrict__ Qb,
    const ushort* __restrict__ Kb, const float* __restrict__ tcut,
    const int* __restrict__ flag, uint* __restrict__ ccnt2, int* __restrict__ cidx2) {
  int b = blockIdx.x >> 6;
  if (!flag[b]) return;
  __shared__ __align__(16) char lds[65536];
  int t = blockIdx.x & 63;
  int tm = t >> 3, tn = t & 7;
  int tid = threadIdx.x;
  f32x4 acc[4][4];
  tile_mfma(Qb, Kb, b, tm, tn, tid, lds, acc);
  int w = tid >> 6, lane = tid & 63;
  int wm = (w >> 1) * 64, wn = (w & 1) * 64;
  int lr = lane & 15, lk = lane >> 4;
  float tc = tcut[b];
#pragma unroll
  for (int fm = 0; fm < 4; fm++)
#pragma unroll
    for (int fn = 0; fn < 4; fn++)
#pragma unroll
      for (int r = 0; r < 4; r++) {
        float v = acc[fm][fn][r] * SCALEF;
        if (v >= tc) {
          int mrow = tm * 128 + wm + fm * 16 + lk * 4 + r;
          int ncol = tn * 128 + wn + fn * 16 + lr;
          uint pos = atomicAdd(&ccnt2[b], 1u);
          if (pos < CAND_MAX) cidx2[b * CAND_MAX + pos] = mrow * 1024 + ncol;
        }
      }
}

// ---------------- K4: factored exact rescore, rank-select, softmax, fused MLPs ----
__global__ __launch_bounds__(256) void k_final(const float* __restrict__ x,
    const float* __restrict__ Wq, const float* __restrict__ bq,
    const float* __restrict__ Wk, const float* __restrict__ bk,
    const float* __restrict__ phiW1, const float* __restrict__ phib1,
    const float* __restrict__ phiW2, const float* __restrict__ phib2,
    const float* __restrict__ xiW1, const float* __restrict__ xib1,
    const float* __restrict__ xiW2, const float* __restrict__ xib2,
    const float* __restrict__ rhoW1, const float* __restrict__ rhob1,
    const float* __restrict__ rhoW2, const float* __restrict__ rhob2,
    const uint* __restrict__ ccnt, const int* __restrict__ cidx,
    const uint* __restrict__ ccnt2, const int* __restrict__ cidx2,
    const float* __restrict__ tcut, const int* __restrict__ flag,
    float* __restrict__ out) {
  int b = blockIdx.x;
  int tid = threadIdx.x;
  __shared__ float M16[256];       // Wq @ Wk^T  (16x16)
  __shared__ float uvw[33];        // u[0:16] = Wq@bk, v[16:32] = bq@Wk, [32] = bq.bk
  __shared__ float cval2[SEL_MAX];
  __shared__ int   cidx2s[SEL_MAX];
  __shared__ int   scnt_sh;
  __shared__ float sel_v[64], sel_w[64];
  __shared__ int   sel_l[64], sel_m[64];
  __shared__ float xpair[2048];    // 64 pairs x (16 xl | 16 xm)
  __shared__ float hsv[128], hpv[128];
  __shared__ float vec1[128], vec2[128];
  __shared__ float wsums[2];

  {  // score factorization setup: s = xl^T M16 xm + u.xl + v.xm + c  (then *SCALE)
    int d = tid >> 4, e = tid & 15;
    float s = 0.f;
#pragma unroll 8
    for (int h = 0; h < 128; h++) s += Wq[d * 128 + h] * Wk[e * 128 + h];
    M16[tid] = s;
  }
  if (tid < 16) {
    float s = 0.f;
    for (int h = 0; h < 128; h++) s += Wq[tid * 128 + h] * bk[h];
    uvw[tid] = s;
  } else if (tid < 32) {
    float s = 0.f;
    for (int h = 0; h < 128; h++) s += bq[h] * Wk[(tid - 16) * 128 + h];
    uvw[tid] = s;
  } else if (tid == 32) {
    float s = 0.f;
    for (int h = 0; h < 128; h++) s += bq[h] * bk[h];
    uvw[32] = s;
  }
  if (tid == 0) scnt_sh = 0;
  if (tid < 64) { sel_v[tid] = -1e30f; sel_l[tid] = 0; sel_m[tid] = 0; }
  __syncthreads();

  int fl = flag[b];
  const int* clist = fl ? (cidx2 + (size_t)b * CAND_MAX) : (cidx + (size_t)b * CAND_MAX);
  uint rawc = fl ? ccnt2[b] : ccnt[b];
  int cnt = rawc > CAND_MAX ? CAND_MAX : (int)rawc;
  float tc = tcut[b];

  // exact fp32 rescore via 16x16 factor; compact by refined cutoff (>=64 survive)
  for (int j = tid; j < cnt; j += 256) {
    int idx = clist[j];
    int l = idx >> 10, m = idx & 1023;
    const float* xl = x + ((size_t)b * 1024 + l) * 16;
    const float* xm = x + ((size_t)b * 1024 + m) * 16;
    float a[16], c2[16];
#pragma unroll
    for (int d = 0; d < 16; d += 4) {
      *(float4*)&a[d]  = *(const float4*)&xl[d];
      *(float4*)&c2[d] = *(const float4*)&xm[d];
    }
    float s = uvw[32];
#pragma unroll
    for (int e = 0; e < 16; e++) {
      float y = uvw[16 + e];
#pragma unroll
      for (int d = 0; d < 16; d++) y += a[d] * M16[d * 16 + e];
      s += y * c2[e];
    }
#pragma unroll
    for (int d = 0; d < 16; d++) s += uvw[d] * a[d];
    s *= SCALEF;
    if (s >= tc) {
      int pos = atomicAdd(&scnt_sh, 1);
      if (pos < SEL_MAX) { cval2[pos] = s; cidx2s[pos] = idx; }
    }
  }
  __syncthreads();
  int scnt = scnt_sh < SEL_MAX ? scnt_sh : SEL_MAX;

  // one-shot rank selection (exact top_k tie-break: value desc, index asc)
  for (int j = tid; j < scnt; j += 256) {
    float vj = cval2[j]; int ij = cidx2s[j];
    int rank = 0;
    for (int i = 0; i < scnt; i++) {
      float vi = cval2[i]; int ii = cidx2s[i];
      rank += (vi > vj || (vi == vj && ii < ij)) ? 1 : 0;
    }
    if (rank < 64) { sel_v[rank] = vj; sel_l[rank] = ij >> 10; sel_m[rank] = ij & 1023; }
  }
  __syncthreads();

  // softmax + wsums (tid<64) || xpair staging (all threads)
  if (tid < 64) {
    float e = expf(sel_v[tid] - sel_v[0]);
    float ssum = e;
#pragma unroll
    for (int off = 1; off < 64; off <<= 1) ssum += __shfl_xor(ssum, off);
    float wj = e / ssum;
    sel_w[tid] = wj;
    int isself = (sel_l[tid] == sel_m[tid]) ? 1 : 0;
    float s0 = isself ? wj : 0.f, s1 = isself ? 0.f : wj;
#pragma unroll
    for (int off = 1; off < 64; off <<= 1) { s0 += __shfl_xor(s0, off); s1 += __shfl_xor(s1, off); }
    if (tid == 0) { wsums[0] = s0; wsums[1] = s1; }
  }
  for (int i = tid; i < 2048; i += 256) {
    int j = i >> 5, d = i & 31;
    int r = (d < 16) ? sel_l[j] : sel_m[j];
    xpair[i] = x[((size_t)b * 1024 + r) * 16 + (d & 15)];
  }
  __syncthreads();

  // feature phase: W1 columns in registers, flat j loop, no inner barriers
  if (tid < 128) {
    int h = tid;
    float wcol[16];
#pragma unroll
    for (int d = 0; d < 16; d++) wcol[d] = phiW1[d * 128 + h];
    float bias = phib1[h];
    float accv = 0.f;
    for (int j = 0; j < 64; j++) {
      if (sel_l[j] == sel_m[j]) {
        float a = bias;
#pragma unroll
        for (int d = 0; d < 16; d++) a += xpair[j * 32 + d] * wcol[d];
        accv += sel_w[j] * fmaxf(a, 0.f);
      }
    }
    hsv[h] = accv;
  } else {
    int h = tid - 128;
    float wcol[32];
#pragma unroll
    for (int d = 0; d < 32; d++) wcol[d] = xiW1[d * 128 + h];
    float bias = xib1[h];
    float accv = 0.f;
    for (int j = 0; j < 64; j++) {
      if (sel_l[j] != sel_m[j]) {
        float a = bias;
#pragma unroll
        for (int d = 0; d < 32; d++) a += xpair[j * 32 + d] * wcol[d];
        accv += sel_w[j] * fmaxf(a, 0.f);
      }
    }
    hpv[h] = accv;
  }
  __syncthreads();

  if (tid < 128) {
    float p = wsums[0] * phib2[tid] + wsums[1] * xib2[tid];
#pragma unroll 4
    for (int h = 0; h < 128; h++) p += hsv[h] * phiW2[h * 128 + tid] + hpv[h] * xiW2[h * 128 + tid];
    vec1[tid] = p;
  }
  __syncthreads();
  if (tid < 128) {
    float r = rhob1[tid];
#pragma unroll 4
    for (int h = 0; h < 128; h++) r += vec1[h] * rhoW1[h * 128 + tid];
    vec2[tid] = fmaxf(r, 0.f);
  }
  __syncthreads();
  if (tid < 128) {
    float o = rhob2[tid];
#pragma unroll 4
    for (int h = 0; h < 128; h++) o += vec2[h] * rhoW2[h * 128 + tid];
    out[(size_t)b * 128 + tid] = o;
  }
}

// ---------------- launch ----------------
extern "C" void kernel_launch(void* const* d_in, const int* in_sizes, int n_in,
                              void* d_out, int out_size, void* d_ws, size_t ws_size,
                              hipStream_t stream) {
  (void)in_sizes; (void)n_in; (void)out_size; (void)ws_size;
  const float* x     = (const float*)d_in[0];
  const float* Wq    = (const float*)d_in[1];
  const float* bq    = (const float*)d_in[2];
  const float* Wk    = (const float*)d_in[3];
  const float* bk    = (const float*)d_in[4];
  const float* phiW1 = (const float*)d_in[5];
  const float* phib1 = (const float*)d_in[6];
  const float* phiW2 = (const float*)d_in[7];
  const float* phib2 = (const float*)d_in[8];
  const float* xiW1  = (const float*)d_in[9];
  const float* xib1  = (const float*)d_in[10];
  const float* xiW2  = (const float*)d_in[11];
  const float* xib2  = (const float*)d_in[12];
  const float* rhoW1 = (const float*)d_in[13];
  const float* rhob1 = (const float*)d_in[14];
  const float* rhoW2 = (const float*)d_in[15];
  const float* rhob2 = (const float*)d_in[16];

  // workspace layout (~36.7 MB)
  char* ws = (char*)d_ws;
  ushort* Qb   = (ushort*)(ws);                  // 16 MB
  ushort* Kb   = (ushort*)(ws + 16777216);       // 16 MB
  uint*   hist = (uint*)(ws + 33554432);         // 1 MB
  uint*   ccnt = (uint*)(ws + 34603008);         // 256 B
  float*  tcut = (float*)(ws + 34603264);        // 256 B
  int*    flag = (int*)(ws + 34603520);          // 256 B
  uint*   ccnt2= (uint*)(ws + 34603776);         // 256 B
  int*    cidx = (int*)(ws + 34604032);          // 1 MB
  int*    cidx2= (int*)(ws + 35652608);          // 1 MB

  hipMemsetAsync(ws + 33554432, 0, 1048576 + 1024, stream);   // hist + 4 counter arrays

  k_proj<<<8192, 128, 0, stream>>>(x, Wq, bq, Wk, bk, Qb, Kb);
  k_score_hist<<<64 * 64, 256, 0, stream>>>(Qb, Kb, hist, ccnt, cidx);
  k_thresh<<<64, 256, 0, stream>>>(hist, ccnt, tcut, flag);
  k_fallback<<<64 * 64, 256, 0, stream>>>(Qb, Kb, tcut, flag, ccnt2, cidx2);
  k_final<<<64, 256, 0, stream>>>(x, Wq, bq, Wk, bk,
                                  phiW1, phib1, phiW2, phib2,
                                  xiW1, xib1, xiW2, xib2,
                                  rhoW1, rhob1, rhoW2, rhob2,
                                  ccnt, cidx, ccnt2, cidx2, tcut, flag,
                                  (float*)d_out);
}

// Round 3
// 791.116 us; speedup vs baseline: 1.7373x; 1.7373x over previous
//
#include <hip/hip_runtime.h>
#include <hip/hip_bf16.h>

typedef unsigned int uint;
typedef unsigned short ushort;
typedef __attribute__((ext_vector_type(8))) short short8;   // 8 bf16 (4 VGPRs)
typedef __attribute__((ext_vector_type(4))) float f32x4;

#define SCALEF 0.08838834764831845f   // 128^-0.5
#define NBINS 4096
#define CAND_MAX 4096
#define SEL_MAX 1024
#define MARGIN 0.08f      // >= 2x worst-case bf16 score error (~0.01)
#define T_LOOSE 3.3f      // static collect threshold (s64 ~ 3.8 for this data)
#define HIST_MIN 2.5f     // histogram prefilter

static __device__ __forceinline__ ushort f2bf(float f) {
  uint u = __float_as_uint(f);
  uint r = ((u >> 16) & 1u) + 0x7fffu;   // RNE
  return (ushort)((u + r) >> 16);
}

// ---------------- K0: Q/K projection (fp32 -> bf16), 8 rows per block ----
__global__ __launch_bounds__(128) void k_proj(const float* __restrict__ x,
    const float* __restrict__ Wq, const float* __restrict__ bq,
    const float* __restrict__ Wk, const float* __restrict__ bk,
    ushort* __restrict__ Qb, ushort* __restrict__ Kb) {
  int bid = blockIdx.x;             // rows [bid*8, bid*8+8)
  int h = threadIdx.x;              // 0..127
  __shared__ float xs[128];         // 8 rows x 16
  xs[h] = x[(size_t)bid * 128 + h];
  float wq[16], wk[16];
#pragma unroll
  for (int d = 0; d < 16; d++) { wq[d] = Wq[d * 128 + h]; wk[d] = Wk[d * 128 + h]; }
  float q0 = bq[h], k0 = bk[h];
  __syncthreads();
#pragma unroll
  for (int r = 0; r < 8; r++) {
    float q = q0, k = k0;
#pragma unroll
    for (int d = 0; d < 16; d++) { float xv = xs[r * 16 + d]; q += xv * wq[d]; k += xv * wk[d]; }
    size_t o = (size_t)(bid * 8 + r) * 128 + h;
    Qb[o] = f2bf(q); Kb[o] = f2bf(k);
  }
}

// ---------------- K1: persistent row-panel MFMA pass ----
// Grid 512 = 64 batches x 8 row-panels, XCD-swizzled so each XCD owns 8 whole batches.
// MODE 0: LDS histogram (prefiltered) + loose static-threshold collect.
// MODE 1: fallback collect with refined tcut, early-exit unless flagged.
// Dynamic LDS: A[0,32768) B[32768,65536) hist[65536,81920) (MODE 0 only).
template<int MODE>
__global__ __launch_bounds__(256) void k_score(const ushort* __restrict__ Qb,
    const ushort* __restrict__ Kb, uint* __restrict__ ghist,
    uint* __restrict__ ccnt, int* __restrict__ cidx,
    const float* __restrict__ tcut, const int* __restrict__ flag) {
  int i = blockIdx.x;
  int b = (i & 7) * 8 + ((i >> 3) & 7);   // same XCD (i&7) => same 8 batches
  int tm = i >> 6;
  if (MODE == 1 && !flag[b]) return;
  extern __shared__ __align__(16) char lds[];
  uint* shist = (uint*)(lds + 65536);
  int tid = threadIdx.x;

  if (MODE == 0)
    for (int s = tid; s < NBINS; s += 256) shist[s] = 0;

  // stage A panel (pre-swizzled global read -> linear LDS, chunk c holds gc=c^(row&7))
  const char* Aq = (const char*)(Qb + (size_t)b * 131072) + (size_t)tm * 32768;
#pragma unroll
  for (int s = 0; s < 8; s++) {
    int slot = tid + 256 * s;
    int row = slot >> 4, c = slot & 15, gc = c ^ (row & 7);
    *(uint4*)(lds + row * 256 + c * 16) = *(const uint4*)(Aq + row * 256 + gc * 16);
  }
  // stage B tile 0
  const char* Bk0 = (const char*)(Kb + (size_t)b * 131072);
#pragma unroll
  for (int s = 0; s < 8; s++) {
    int slot = tid + 256 * s;
    int row = slot >> 4, c = slot & 15, gc = c ^ (row & 7);
    *(uint4*)(lds + 32768 + row * 256 + c * 16) = *(const uint4*)(Bk0 + row * 256 + gc * 16);
  }
  __syncthreads();

  int w = tid >> 6, lane = tid & 63;
  int wm = (w >> 1) * 64, wn = (w & 1) * 64;   // 2x2 wave grid, 64x64 each
  int lr = lane & 15, lk = lane >> 4;

  // hoist A fragments (iteration-invariant): af[ks][f]
  short8 af[4][4];
#pragma unroll
  for (int ks = 0; ks < 4; ks++)
#pragma unroll
    for (int f = 0; f < 4; f++) {
      int ra = wm + f * 16 + lr;
      int ca = (ks * 4 + lk) ^ (ra & 7);
      af[ks][f] = *(const short8*)(lds + ra * 256 + ca * 16);
    }

  float tc = (MODE == 1) ? tcut[b] : 0.f;

  for (int tn = 0; tn < 8; tn++) {
    f32x4 acc[4][4];
#pragma unroll
    for (int a2 = 0; a2 < 4; a2++)
#pragma unroll
      for (int c2 = 0; c2 < 4; c2++) acc[a2][c2] = (f32x4){0.f, 0.f, 0.f, 0.f};
#pragma unroll
    for (int ks = 0; ks < 4; ks++) {
      short8 bf2[4];
#pragma unroll
      for (int f = 0; f < 4; f++) {
        int rb = wn + f * 16 + lr;
        int cb = (ks * 4 + lk) ^ (rb & 7);
        bf2[f] = *(const short8*)(lds + 32768 + rb * 256 + cb * 16);
      }
#pragma unroll
      for (int fm = 0; fm < 4; fm++)
#pragma unroll
        for (int fn = 0; fn < 4; fn++)
          acc[fm][fn] = __builtin_amdgcn_mfma_f32_16x16x32_bf16(af[ks][fm], bf2[fn], acc[fm][fn], 0, 0, 0);
    }

    // epilogue for this tile
#pragma unroll
    for (int fm = 0; fm < 4; fm++)
#pragma unroll
      for (int fn = 0; fn < 4; fn++)
#pragma unroll
        for (int r = 0; r < 4; r++) {
          float v = acc[fm][fn][r] * SCALEF;
          if (MODE == 0) {
            if (v >= HIST_MIN) {
              uint u = __float_as_uint(v) | 0x80000000u;   // order-map (v>0 here)
              atomicAdd(&shist[u >> 20], 1u);
              if (v >= T_LOOSE) {
                int mrow = tm * 128 + wm + fm * 16 + lk * 4 + r;
                int ncol = tn * 128 + wn + fn * 16 + lr;
                uint pos = atomicAdd(&ccnt[b], 1u);
                if (pos < CAND_MAX) cidx[b * CAND_MAX + pos] = mrow * 1024 + ncol;
              }
            }
          } else {
            if (v >= tc) {
              int mrow = tm * 128 + wm + fm * 16 + lk * 4 + r;
              int ncol = tn * 128 + wn + fn * 16 + lr;
              uint pos = atomicAdd(&ccnt[b], 1u);
              if (pos < CAND_MAX) cidx[b * CAND_MAX + pos] = mrow * 1024 + ncol;
            }
          }
        }

    if (tn < 7) {
      __syncthreads();               // everyone done reading B tile tn
      const char* Bk = (const char*)(Kb + (size_t)b * 131072) + (size_t)(tn + 1) * 32768;
#pragma unroll
      for (int s = 0; s < 8; s++) {
        int slot = tid + 256 * s;
        int row = slot >> 4, c = slot & 15, gc = c ^ (row & 7);
        *(uint4*)(lds + 32768 + row * 256 + c * 16) = *(const uint4*)(Bk + row * 256 + gc * 16);
      }
      __syncthreads();
    }
  }

  if (MODE == 0) {                   // aggregated per-block flush (few nonzero bins)
    __syncthreads();
    for (int s = tid; s < NBINS; s += 256) {
      uint c2 = shist[s];
      if (c2) atomicAdd(&ghist[b * NBINS + s], c2);
    }
  }
}

// ---------------- K2: refined threshold + safety verification ----
__global__ __launch_bounds__(256) void k_thresh(const uint* __restrict__ ghist,
    const uint* __restrict__ ccnt, float* __restrict__ tcut, int* __restrict__ flag) {
  int b = blockIdx.x;
  int tid = threadIdx.x;
  __shared__ uint hsh[NBINS];
  __shared__ uint csuf[256];
  __shared__ uint total_sh;
  for (int i = tid; i < NBINS; i += 256) hsh[i] = ghist[b * NBINS + i];
  __syncthreads();
  uint s = 0;
#pragma unroll
  for (int i = 0; i < 16; i++) s += hsh[tid * 16 + i];
  csuf[tid] = s;
  __syncthreads();
  if (tid == 0) {                      // exclusive suffix over 256 chunk sums
    uint run = 0;
    for (int t2 = 255; t2 >= 0; t2--) { uint tmp = csuf[t2]; csuf[t2] = run; run += tmp; }
    total_sh = run;
  }
  __syncthreads();
  if (total_sh < 64) {                 // degenerate: 64th value below HIST_MIN
    if (tid == 0) { tcut[b] = -1e30f; flag[b] = 1; }
    return;
  }
  uint above = csuf[tid];
  if (above < 64) {
    uint run = above;
    for (int i = 15; i >= 0; i--) {
      run += hsh[tid * 16 + i];
      if (run >= 64) {                 // bin containing the 64th-largest approx value
        uint umin = ((uint)(tid * 16 + i)) << 20;
        float lower = (umin & 0x80000000u) ? __uint_as_float(umin ^ 0x80000000u)
                                           : __uint_as_float(~umin);
        tcut[b] = lower - MARGIN;
        // pass-0 candidate set valid iff every true-top-64's approx >= T_LOOSE
        flag[b] = (lower < T_LOOSE + MARGIN) || (ccnt[b] > CAND_MAX) ? 1 : 0;
        break;
      }
    }
  }
}

// ---------------- K4: factored exact rescore, rank-select, softmax, fused MLPs ----
__global__ __launch_bounds__(256) void k_final(const float* __restrict__ x,
    const float* __restrict__ Wq, const float* __restrict__ bq,
    const float* __restrict__ Wk, const float* __restrict__ bk,
    const float* __restrict__ phiW1, const float* __restrict__ phib1,
    const float* __restrict__ phiW2, const float* __restrict__ phib2,
    const float* __restrict__ xiW1, const float* __restrict__ xib1,
    const float* __restrict__ xiW2, const float* __restrict__ xib2,
    const float* __restrict__ rhoW1, const float* __restrict__ rhob1,
    const float* __restrict__ rhoW2, const float* __restrict__ rhob2,
    const uint* __restrict__ ccnt, const int* __restrict__ cidx,
    const uint* __restrict__ ccnt2, const int* __restrict__ cidx2,
    const float* __restrict__ tcut, const int* __restrict__ flag,
    float* __restrict__ out) {
  int b = blockIdx.x;
  int tid = threadIdx.x;
  __shared__ float M16[256];       // Wq @ Wk^T  (16x16)
  __shared__ float uvw[33];        // u[0:16] = Wq@bk, v[16:32] = bq@Wk, [32] = bq.bk
  __shared__ float cval2[SEL_MAX];
  __shared__ int   cidx2s[SEL_MAX];
  __shared__ int   scnt_sh;
  __shared__ float sel_v[64], sel_w[64];
  __shared__ int   sel_l[64], sel_m[64];
  __shared__ float xpair[2048];    // 64 pairs x (16 xl | 16 xm)
  __shared__ float hsv[128], hpv[128];
  __shared__ float vec1[128], vec2[128];
  __shared__ float wsums[2];

  {  // score factorization setup: s = xl^T M16 xm + u.xl + v.xm + c  (then *SCALE)
    int d = tid >> 4, e = tid & 15;
    float s = 0.f;
#pragma unroll 8
    for (int h = 0; h < 128; h++) s += Wq[d * 128 + h] * Wk[e * 128 + h];
    M16[tid] = s;
  }
  if (tid < 16) {
    float s = 0.f;
    for (int h = 0; h < 128; h++) s += Wq[tid * 128 + h] * bk[h];
    uvw[tid] = s;
  } else if (tid < 32) {
    float s = 0.f;
    for (int h = 0; h < 128; h++) s += bq[h] * Wk[(tid - 16) * 128 + h];
    uvw[tid] = s;
  } else if (tid == 32) {
    float s = 0.f;
    for (int h = 0; h < 128; h++) s += bq[h] * bk[h];
    uvw[32] = s;
  }
  if (tid == 0) scnt_sh = 0;
  if (tid < 64) { sel_v[tid] = -1e30f; sel_l[tid] = 0; sel_m[tid] = 0; }
  __syncthreads();

  int fl = flag[b];
  const int* clist = fl ? (cidx2 + (size_t)b * CAND_MAX) : (cidx + (size_t)b * CAND_MAX);
  uint rawc = fl ? ccnt2[b] : ccnt[b];
  int cnt = rawc > CAND_MAX ? CAND_MAX : (int)rawc;
  float tc = tcut[b];

  // exact fp32 rescore via 16x16 factor; compact by refined cutoff (>=64 survive)
  for (int j = tid; j < cnt; j += 256) {
    int idx = clist[j];
    int l = idx >> 10, m = idx & 1023;
    const float* xl = x + ((size_t)b * 1024 + l) * 16;
    const float* xm = x + ((size_t)b * 1024 + m) * 16;
    float a[16], c2[16];
#pragma unroll
    for (int d = 0; d < 16; d += 4) {
      *(float4*)&a[d]  = *(const float4*)&xl[d];
      *(float4*)&c2[d] = *(const float4*)&xm[d];
    }
    float s = uvw[32];
#pragma unroll
    for (int e = 0; e < 16; e++) {
      float y = uvw[16 + e];
#pragma unroll
      for (int d = 0; d < 16; d++) y += a[d] * M16[d * 16 + e];
      s += y * c2[e];
    }
#pragma unroll
    for (int d = 0; d < 16; d++) s += uvw[d] * a[d];
    s *= SCALEF;
    if (s >= tc) {
      int pos = atomicAdd(&scnt_sh, 1);
      if (pos < SEL_MAX) { cval2[pos] = s; cidx2s[pos] = idx; }
    }
  }
  __syncthreads();
  int scnt = scnt_sh < SEL_MAX ? scnt_sh : SEL_MAX;

  // one-shot rank selection (exact top_k tie-break: value desc, index asc)
  for (int j = tid; j < scnt; j += 256) {
    float vj = cval2[j]; int ij = cidx2s[j];
    int rank = 0;
    for (int i = 0; i < scnt; i++) {
      float vi = cval2[i]; int ii = cidx2s[i];
      rank += (vi > vj || (vi == vj && ii < ij)) ? 1 : 0;
    }
    if (rank < 64) { sel_v[rank] = vj; sel_l[rank] = ij >> 10; sel_m[rank] = ij & 1023; }
  }
  __syncthreads();

  // softmax + wsums (tid<64) || xpair staging (all threads)
  if (tid < 64) {
    float e = expf(sel_v[tid] - sel_v[0]);
    float ssum = e;
#pragma unroll
    for (int off = 1; off < 64; off <<= 1) ssum += __shfl_xor(ssum, off);
    float wj = e / ssum;
    sel_w[tid] = wj;
    int isself = (sel_l[tid] == sel_m[tid]) ? 1 : 0;
    float s0 = isself ? wj : 0.f, s1 = isself ? 0.f : wj;
#pragma unroll
    for (int off = 1; off < 64; off <<= 1) { s0 += __shfl_xor(s0, off); s1 += __shfl_xor(s1, off); }
    if (tid == 0) { wsums[0] = s0; wsums[1] = s1; }
  }
  for (int i = tid; i < 2048; i += 256) {
    int j = i >> 5, d = i & 31;
    int r = (d < 16) ? sel_l[j] : sel_m[j];
    xpair[i] = x[((size_t)b * 1024 + r) * 16 + (d & 15)];
  }
  __syncthreads();

  // feature phase: W1 columns in registers, flat j loop, no inner barriers
  if (tid < 128) {
    int h = tid;
    float wcol[16];
#pragma unroll
    for (int d = 0; d < 16; d++) wcol[d] = phiW1[d * 128 + h];
    float bias = phib1[h];
    float accv = 0.f;
    for (int j = 0; j < 64; j++) {
      if (sel_l[j] == sel_m[j]) {
        float a = bias;
#pragma unroll
        for (int d = 0; d < 16; d++) a += xpair[j * 32 + d] * wcol[d];
        accv += sel_w[j] * fmaxf(a, 0.f);
      }
    }
    hsv[h] = accv;
  } else {
    int h = tid - 128;
    float wcol[32];
#pragma unroll
    for (int d = 0; d < 32; d++) wcol[d] = xiW1[d * 128 + h];
    float bias = xib1[h];
    float accv = 0.f;
    for (int j = 0; j < 64; j++) {
      if (sel_l[j] != sel_m[j]) {
        float a = bias;
#pragma unroll
        for (int d = 0; d < 32; d++) a += xpair[j * 32 + d] * wcol[d];
        accv += sel_w[j] * fmaxf(a, 0.f);
      }
    }
    hpv[h] = accv;
  }
  __syncthreads();

  if (tid < 128) {
    float p = wsums[0] * phib2[tid] + wsums[1] * xib2[tid];
#pragma unroll 4
    for (int h = 0; h < 128; h++) p += hsv[h] * phiW2[h * 128 + tid] + hpv[h] * xiW2[h * 128 + tid];
    vec1[tid] = p;
  }
  __syncthreads();
  if (tid < 128) {
    float r = rhob1[tid];
#pragma unroll 4
    for (int h = 0; h < 128; h++) r += vec1[h] * rhoW1[h * 128 + tid];
    vec2[tid] = fmaxf(r, 0.f);
  }
  __syncthreads();
  if (tid < 128) {
    float o = rhob2[tid];
#pragma unroll 4
    for (int h = 0; h < 128; h++) o += vec2[h] * rhoW2[h * 128 + tid];
    out[(size_t)b * 128 + tid] = o;
  }
}

// ---------------- launch ----------------
extern "C" void kernel_launch(void* const* d_in, const int* in_sizes, int n_in,
                              void* d_out, int out_size, void* d_ws, size_t ws_size,
                              hipStream_t stream) {
  (void)in_sizes; (void)n_in; (void)out_size; (void)ws_size;
  const float* x     = (const float*)d_in[0];
  const float* Wq    = (const float*)d_in[1];
  const float* bq    = (const float*)d_in[2];
  const float* Wk    = (const float*)d_in[3];
  const float* bk    = (const float*)d_in[4];
  const float* phiW1 = (const float*)d_in[5];
  const float* phib1 = (const float*)d_in[6];
  const float* phiW2 = (const float*)d_in[7];
  const float* phib2 = (const float*)d_in[8];
  const float* xiW1  = (const float*)d_in[9];
  const float* xib1  = (const float*)d_in[10];
  const float* xiW2  = (const float*)d_in[11];
  const float* xib2  = (const float*)d_in[12];
  const float* rhoW1 = (const float*)d_in[13];
  const float* rhob1 = (const float*)d_in[14];
  const float* rhoW2 = (const float*)d_in[15];
  const float* rhob2 = (const float*)d_in[16];

  // workspace layout (~36.7 MB)
  char* ws = (char*)d_ws;
  ushort* Qb   = (ushort*)(ws);                  // 16 MB
  ushort* Kb   = (ushort*)(ws + 16777216);       // 16 MB
  uint*   hist = (uint*)(ws + 33554432);         // 1 MB
  uint*   ccnt = (uint*)(ws + 34603008);         // 256 B
  float*  tcut = (float*)(ws + 34603264);        // 256 B
  int*    flag = (int*)(ws + 34603520);          // 256 B
  uint*   ccnt2= (uint*)(ws + 34603776);         // 256 B
  int*    cidx = (int*)(ws + 34604032);          // 1 MB
  int*    cidx2= (int*)(ws + 35652608);          // 1 MB

  hipMemsetAsync(ws + 33554432, 0, 1048576 + 1024, stream);   // hist + counters

  k_proj<<<8192, 128, 0, stream>>>(x, Wq, bq, Wk, bk, Qb, Kb);
  k_score<0><<<512, 256, 81920, stream>>>(Qb, Kb, hist, ccnt, cidx, nullptr, nullptr);
  k_thresh<<<64, 256, 0, stream>>>(hist, ccnt, tcut, flag);
  k_score<1><<<512, 256, 65536, stream>>>(Qb, Kb, nullptr, ccnt2, cidx2, tcut, flag);
  k_final<<<64, 256, 0, stream>>>(x, Wq, bq, Wk, bk,
                                  phiW1, phib1, phiW2, phib2,
                                  xiW1, xib1, xiW2, xib2,
                                  rhoW1, rhob1, rhoW2, rhob2,
                                  ccnt, cidx, ccnt2, cidx2, tcut, flag,
                                  (float*)d_out);
}

// Round 4
// 249.849 us; speedup vs baseline: 5.5008x; 3.1664x over previous
//
#include <hip/hip_runtime.h>

typedef unsigned int uint;

#define SCALEF 0.08838834764831845f   // 128^-0.5
#define NBINS 4096
#define CAND_MAX 4096
#define SEL_MAX 1024
#define LLIST 512
#define T_LOOSE 3.3f      // static collect threshold (s64 ~ 11+ for this data)
#define HIST_MIN 2.5f     // histogram prefilter

// ---------------- K_prep: factored score basis ----------------
// s(l,m) = g_l . x_m + h_l   (exact fp32, SCALEF folded in)
// g_l = SCALE*(A^T x_l + v), h_l = SCALE*(u.x_l + c),
// A = Wq Wk^T (16x16), u = Wq bk, v = Wk^T... v_e = bq.Wk[e,:], c = bq.bk
__global__ __launch_bounds__(256) void k_prep(const float* __restrict__ x,
    const float* __restrict__ Wq, const float* __restrict__ bq,
    const float* __restrict__ Wk, const float* __restrict__ bk,
    float* __restrict__ Gv, float* __restrict__ Hv) {
  __shared__ float sWq[2048], sWk[2048];
  __shared__ float sA[256];
  __shared__ float su[16], sv[16], sc;
  int tid = threadIdx.x;
  for (int i = tid; i < 512; i += 256) {
    ((float4*)sWq)[i] = ((const float4*)Wq)[i];
    ((float4*)sWk)[i] = ((const float4*)Wk)[i];
  }
  __syncthreads();
  {
    int d = tid >> 4, e = tid & 15;
    float s = 0.f;
#pragma unroll 8
    for (int h = 0; h < 128; h++) s += sWq[d * 128 + h] * sWk[e * 128 + h];
    sA[tid] = s * SCALEF;
  }
  if (tid < 16) {
    float s1 = 0.f, s2 = 0.f;
    for (int h = 0; h < 128; h++) { s1 += sWq[tid * 128 + h] * bk[h]; s2 += bq[h] * sWk[tid * 128 + h]; }
    su[tid] = s1 * SCALEF; sv[tid] = s2 * SCALEF;
  } else if (tid == 16) {
    float s = 0.f;
    for (int h = 0; h < 128; h++) s += bq[h] * bk[h];
    sc = s * SCALEF;
  }
  __syncthreads();
  int row = blockIdx.x * 256 + tid;      // 0..65535 (b*1024+l)
  float xr[16];
#pragma unroll
  for (int d = 0; d < 16; d += 4) *(float4*)&xr[d] = *(const float4*)&x[(size_t)row * 16 + d];
  float g[16];
#pragma unroll
  for (int e = 0; e < 16; e++) {
    float s = sv[e];
#pragma unroll
    for (int d = 0; d < 16; d++) s += xr[d] * sA[d * 16 + e];
    g[e] = s;
  }
  float hh = sc;
#pragma unroll
  for (int d = 0; d < 16; d++) hh += xr[d] * su[d];
#pragma unroll
  for (int e = 0; e < 16; e += 4) *(float4*)&Gv[(size_t)row * 16 + e] = *(float4*)&g[e];
  Hv[row] = hh;
}

// ---------------- K1: exact fp32 score tiles (4096 blocks, 128x128 each) ----
// MODE 0: prefiltered LDS hist + loose collect (with values).
// MODE 1: fallback collect with refined tcut, early-exit unless flagged.
template<int MODE>
__global__ __launch_bounds__(256) void k_score(const float* __restrict__ Gv,
    const float* __restrict__ Hv, const float* __restrict__ x,
    uint* __restrict__ ghist, uint* __restrict__ ccnt,
    int* __restrict__ cidx, float* __restrict__ cval,
    const float* __restrict__ tcut, const int* __restrict__ flag) {
  int i = blockIdx.x;
  int b = i >> 6, t = i & 63, tm = t >> 3, tn = t & 7;
  if (MODE == 1 && !flag[b]) return;
  __shared__ float sG[2048];          // 128 rows x 16
  __shared__ float sX[2048];          // 128 cols x 16
  __shared__ float sH[128];
  __shared__ int   lidx[LLIST];
  __shared__ float lval[LLIST];
  __shared__ uint  lcnt;
  __shared__ uint  base_sh;
  __shared__ uint  shist[MODE == 0 ? NBINS : 1];
  int tid = threadIdx.x;

  if (MODE == 0)
    for (int s = tid; s < NBINS; s += 256) shist[s] = 0;
  if (tid == 0) lcnt = 0;
  const float4* gsrc = (const float4*)(Gv + ((size_t)b * 1024 + tm * 128) * 16);
  const float4* xsrc = (const float4*)(x + ((size_t)b * 1024 + tn * 128) * 16);
  for (int s = tid; s < 512; s += 256) { ((float4*)sG)[s] = gsrc[s]; ((float4*)sX)[s] = xsrc[s]; }
  if (tid < 128) sH[tid] = Hv[b * 1024 + tm * 128 + tid];
  __syncthreads();

  int w = tid >> 6, lane = tid & 63;
  int r = (w >> 1) * 64 + lane;        // row within tile (per-lane)
  int cb = (w & 1) * 64;               // col base (per-wave)
  float g[16];
#pragma unroll
  for (int d = 0; d < 16; d++) g[d] = sG[r * 16 + d];
  float hh = sH[r];
  float tc = (MODE == 1) ? tcut[b] : T_LOOSE;

  for (int c2 = 0; c2 < 64; c2++) {
    int m = cb + c2;
    const float* xm = &sX[m * 16];     // uniform per wave -> LDS broadcast
    float s = hh;
#pragma unroll
    for (int d = 0; d < 16; d++) s += g[d] * xm[d];
    if (MODE == 0 && s >= HIST_MIN) {
      uint u = __float_as_uint(s) | 0x80000000u;   // order-map (s>0 here)
      atomicAdd(&shist[u >> 20], 1u);
    }
    if (s >= tc) {
      uint pos = atomicAdd(&lcnt, 1u);
      int fi = (tm * 128 + r) * 1024 + (tn * 128 + m);
      if (pos < LLIST) { lidx[pos] = fi; lval[pos] = s; }
      else {                            // rare spill: direct global
        uint gp = atomicAdd(&ccnt[b], 1u);
        if (gp < CAND_MAX) { cidx[b * CAND_MAX + gp] = fi; cval[b * CAND_MAX + gp] = s; }
      }
    }
  }
  __syncthreads();
  if (MODE == 0)
    for (int s = tid; s < NBINS; s += 256) { uint c3 = shist[s]; if (c3) atomicAdd(&ghist[b * NBINS + s], c3); }
  uint n = lcnt; if (n > LLIST) n = LLIST;
  if (tid == 0) base_sh = atomicAdd(&ccnt[b], n);   // ONE global atomic per block
  __syncthreads();
  uint base = base_sh;
  for (uint j = tid; j < n; j += 256) {
    uint p = base + j;
    if (p < CAND_MAX) { cidx[b * CAND_MAX + p] = lidx[j]; cval[b * CAND_MAX + p] = lval[j]; }
  }
}

// ---------------- K2: exact threshold from histogram + safety verification ----
__global__ __launch_bounds__(256) void k_thresh(const uint* __restrict__ ghist,
    const uint* __restrict__ ccnt, float* __restrict__ tcut, int* __restrict__ flag) {
  int b = blockIdx.x;
  int tid = threadIdx.x;
  __shared__ uint hsh[NBINS];
  __shared__ uint csuf[256];
  __shared__ uint total_sh;
  for (int i = tid; i < NBINS; i += 256) hsh[i] = ghist[b * NBINS + i];
  __syncthreads();
  uint s = 0;
#pragma unroll
  for (int i = 0; i < 16; i++) s += hsh[tid * 16 + i];
  csuf[tid] = s;
  __syncthreads();
  if (tid == 0) {                      // exclusive suffix over 256 chunk sums
    uint run = 0;
    for (int t2 = 255; t2 >= 0; t2--) { uint tmp = csuf[t2]; csuf[t2] = run; run += tmp; }
    total_sh = run;
  }
  __syncthreads();
  if (total_sh < 64) {                 // degenerate: 64th value below HIST_MIN
    if (tid == 0) { tcut[b] = -1e30f; flag[b] = 1; }
    return;
  }
  uint above = csuf[tid];
  if (above < 64) {
    uint run = above;
    for (int i = 15; i >= 0; i--) {
      run += hsh[tid * 16 + i];
      if (run >= 64) {                 // bin containing the 64th-largest value (exact scores)
        uint umin = ((uint)(tid * 16 + i)) << 20;
        float lower = (umin & 0x80000000u) ? __uint_as_float(umin ^ 0x80000000u)
                                           : __uint_as_float(~umin);
        tcut[b] = lower;               // true lower bound of s64 -> MARGIN 0
        flag[b] = (lower < T_LOOSE) || (ccnt[b] > CAND_MAX) ? 1 : 0;
        break;
      }
    }
  }
}

// ---------------- K4: compact, rank-select top-64, softmax, fused MLPs ----
__global__ __launch_bounds__(256) void k_final(const float* __restrict__ x,
    const float* __restrict__ phiW1, const float* __restrict__ phib1,
    const float* __restrict__ phiW2, const float* __restrict__ phib2,
    const float* __restrict__ xiW1, const float* __restrict__ xib1,
    const float* __restrict__ xiW2, const float* __restrict__ xib2,
    const float* __restrict__ rhoW1, const float* __restrict__ rhob1,
    const float* __restrict__ rhoW2, const float* __restrict__ rhob2,
    const uint* __restrict__ ccnt, const int* __restrict__ cidx, const float* __restrict__ cval,
    const uint* __restrict__ ccnt2, const int* __restrict__ cidx2, const float* __restrict__ cval2g,
    const float* __restrict__ tcut, const int* __restrict__ flag,
    float* __restrict__ out) {
  int b = blockIdx.x;
  int tid = threadIdx.x;
  __shared__ float cv[SEL_MAX];
  __shared__ int   ci[SEL_MAX];
  __shared__ int   scnt_sh;
  __shared__ float sel_v[64], sel_w[64];
  __shared__ int   sel_l[64], sel_m[64];
  __shared__ float xpair[2048];    // 64 pairs x (16 xl | 16 xm)
  __shared__ float hsv[128], hpv[128];
  __shared__ float vec1[128], vec2[128];
  __shared__ float wsums[2];

  if (tid == 0) scnt_sh = 0;
  if (tid < 64) { sel_v[tid] = -1e30f; sel_l[tid] = 0; sel_m[tid] = 0; }
  __syncthreads();

  int fl = flag[b];
  const int*   clist = fl ? (cidx2 + (size_t)b * CAND_MAX) : (cidx + (size_t)b * CAND_MAX);
  const float* vlist = fl ? (cval2g + (size_t)b * CAND_MAX) : (cval + (size_t)b * CAND_MAX);
  uint rawc = fl ? ccnt2[b] : ccnt[b];
  int cnt = rawc > CAND_MAX ? CAND_MAX : (int)rawc;
  float tc = tcut[b];

  // compact by exact cutoff (all true top-64 survive)
  for (int j = tid; j < cnt; j += 256) {
    float v = vlist[j];
    if (v >= tc) {
      int pos = atomicAdd(&scnt_sh, 1);
      if (pos < SEL_MAX) { cv[pos] = v; ci[pos] = clist[j]; }
    }
  }
  __syncthreads();
  int scnt = scnt_sh < SEL_MAX ? scnt_sh : SEL_MAX;

  // one-shot rank selection (exact top_k tie-break: value desc, index asc)
  for (int j = tid; j < scnt; j += 256) {
    float vj = cv[j]; int ij = ci[j];
    int rank = 0;
    for (int i = 0; i < scnt; i++) {
      float vi = cv[i]; int ii = ci[i];
      rank += (vi > vj || (vi == vj && ii < ij)) ? 1 : 0;
    }
    if (rank < 64) { sel_v[rank] = vj; sel_l[rank] = ij >> 10; sel_m[rank] = ij & 1023; }
  }
  __syncthreads();

  // softmax + wsums (tid<64) || xpair staging (all threads)
  if (tid < 64) {
    float e = expf(sel_v[tid] - sel_v[0]);
    float ssum = e;
#pragma unroll
    for (int off = 1; off < 64; off <<= 1) ssum += __shfl_xor(ssum, off);
    float wj = e / ssum;
    sel_w[tid] = wj;
    int isself = (sel_l[tid] == sel_m[tid]) ? 1 : 0;
    float s0 = isself ? wj : 0.f, s1 = isself ? 0.f : wj;
#pragma unroll
    for (int off = 1; off < 64; off <<= 1) { s0 += __shfl_xor(s0, off); s1 += __shfl_xor(s1, off); }
    if (tid == 0) { wsums[0] = s0; wsums[1] = s1; }
  }
  for (int i = tid; i < 2048; i += 256) {
    int j = i >> 5, d = i & 31;
    int r = (d < 16) ? sel_l[j] : sel_m[j];
    xpair[i] = x[((size_t)b * 1024 + r) * 16 + (d & 15)];
  }
  __syncthreads();

  // feature phase: W1 columns in registers, flat j loop, no inner barriers
  if (tid < 128) {
    int h = tid;
    float wcol[16];
#pragma unroll
    for (int d = 0; d < 16; d++) wcol[d] = phiW1[d * 128 + h];
    float bias = phib1[h];
    float accv = 0.f;
    for (int j = 0; j < 64; j++) {
      if (sel_l[j] == sel_m[j]) {
        float a = bias;
#pragma unroll
        for (int d = 0; d < 16; d++) a += xpair[j * 32 + d] * wcol[d];
        accv += sel_w[j] * fmaxf(a, 0.f);
      }
    }
    hsv[h] = accv;
  } else {
    int h = tid - 128;
    float wcol[32];
#pragma unroll
    for (int d = 0; d < 32; d++) wcol[d] = xiW1[d * 128 + h];
    float bias = xib1[h];
    float accv = 0.f;
    for (int j = 0; j < 64; j++) {
      if (sel_l[j] != sel_m[j]) {
        float a = bias;
#pragma unroll
        for (int d = 0; d < 32; d++) a += xpair[j * 32 + d] * wcol[d];
        accv += sel_w[j] * fmaxf(a, 0.f);
      }
    }
    hpv[h] = accv;
  }
  __syncthreads();

  if (tid < 128) {
    float p = wsums[0] * phib2[tid] + wsums[1] * xib2[tid];
#pragma unroll 4
    for (int h = 0; h < 128; h++) p += hsv[h] * phiW2[h * 128 + tid] + hpv[h] * xiW2[h * 128 + tid];
    vec1[tid] = p;
  }
  __syncthreads();
  if (tid < 128) {
    float r = rhob1[tid];
#pragma unroll 4
    for (int h = 0; h < 128; h++) r += vec1[h] * rhoW1[h * 128 + tid];
    vec2[tid] = fmaxf(r, 0.f);
  }
  __syncthreads();
  if (tid < 128) {
    float o = rhob2[tid];
#pragma unroll 4
    for (int h = 0; h < 128; h++) o += vec2[h] * rhoW2[h * 128 + tid];
    out[(size_t)b * 128 + tid] = o;
  }
}

// ---------------- launch ----------------
extern "C" void kernel_launch(void* const* d_in, const int* in_sizes, int n_in,
                              void* d_out, int out_size, void* d_ws, size_t ws_size,
                              hipStream_t stream) {
  (void)in_sizes; (void)n_in; (void)out_size; (void)ws_size;
  const float* x     = (const float*)d_in[0];
  const float* Wq    = (const float*)d_in[1];
  const float* bq    = (const float*)d_in[2];
  const float* Wk    = (const float*)d_in[3];
  const float* bk    = (const float*)d_in[4];
  const float* phiW1 = (const float*)d_in[5];
  const float* phib1 = (const float*)d_in[6];
  const float* phiW2 = (const float*)d_in[7];
  const float* phib2 = (const float*)d_in[8];
  const float* xiW1  = (const float*)d_in[9];
  const float* xib1  = (const float*)d_in[10];
  const float* xiW2  = (const float*)d_in[11];
  const float* xib2  = (const float*)d_in[12];
  const float* rhoW1 = (const float*)d_in[13];
  const float* rhob1 = (const float*)d_in[14];
  const float* rhoW2 = (const float*)d_in[15];
  const float* rhob2 = (const float*)d_in[16];

  // workspace layout (~9.7 MB)
  char* ws = (char*)d_ws;
  float* Gv   = (float*)(ws);                      // 4 MB
  float* Hv   = (float*)(ws + 4194304);            // 256 KB
  uint*  ccnt = (uint*)(ws + 4456448);             // 256 B
  uint*  ccnt2= (uint*)(ws + 4456704);             // 256 B
  int*   flag = (int*)(ws + 4456960);              // 256 B (+256 pad)
  uint*  hist = (uint*)(ws + 4457472);             // 1 MB
  float* tcut = (float*)(ws + 5506048);            // 256 B
  int*   cidx = (int*)(ws + 5506304);              // 1 MB
  float* cval = (float*)(ws + 6554880);            // 1 MB
  int*   cidx2= (int*)(ws + 7603456);              // 1 MB
  float* cval2= (float*)(ws + 8652032);            // 1 MB

  hipMemsetAsync(ws + 4456448, 0, 1024 + 1048576, stream);   // counters+flag+pad+hist

  k_prep<<<256, 256, 0, stream>>>(x, Wq, bq, Wk, bk, Gv, Hv);
  k_score<0><<<4096, 256, 0, stream>>>(Gv, Hv, x, hist, ccnt, cidx, cval, nullptr, nullptr);
  k_thresh<<<64, 256, 0, stream>>>(hist, ccnt, tcut, flag);
  k_score<1><<<4096, 256, 0, stream>>>(Gv, Hv, x, nullptr, ccnt2, cidx2, cval2, tcut, flag);
  k_final<<<64, 256, 0, stream>>>(x,
                                  phiW1, phib1, phiW2, phib2,
                                  xiW1, xib1, xiW2, xib2,
                                  rhoW1, rhob1, rhoW2, rhob2,
                                  ccnt, cidx, cval, ccnt2, cidx2, cval2, tcut, flag,
                                  (float*)d_out);
}